// Round 3
// baseline (132.738 us; speedup 1.0000x reference)
//
#include <hip/hip_runtime.h>
#include <hip/hip_bf16.h>

#define NB 8
#define NN 256
#define DD 64

// workspace layout (float offsets)
#define OFF_WCSW  0        // 2048 floats = 4096 bf16: B-fragments of Wc, swizzled
#define OFF_CSA   2048     // 1024 : Wv1 row0 swizzled to A-frag lane order
#define OFF_CSB   3072     // 1024 : Wv1 row1 swizzled
#define OFF_CSC   4096     // 1024 : bv1 swizzled
#define OFF_CC    5120     // 64   : cc[d] = 0.5*(bv2@Ws1)[d] + bs1[d]
#define OFF_M     5184     // 8    : per-batch max as monotonic-uint keys
#define OFF_Z     5192     // 8    : per-batch softmax denominator
#define OFF_SH    5200     // 512  : Sh[b][k]  = sum_ij w_ij h_ij[k]
#define OFF_A2    5712     // 512  : A2[b][d]  = sum_i rowsum_i * v[i][d]
#define OFF_U     7296     // 131072 : u[b][i][d] = 0.25*(v@Ws1)
#define OFF_SC    138368   // 524288 : scores[b][i][j]

typedef __attribute__((ext_vector_type(4))) float f32x4;
typedef __attribute__((ext_vector_type(8))) short s16x8;

static __device__ __forceinline__ unsigned short bf16_rn(float x) {
    unsigned u = __float_as_uint(x);
    u += 0x8000u;
    return (unsigned short)(u >> 16);
}

// ---------------------------------------------------------------- setup ----
__global__ __launch_bounds__(256) void k_setup(
    const float* __restrict__ values, const float* __restrict__ Wv1,
    const float* __restrict__ bv1, const float* __restrict__ Wv2,
    const float* __restrict__ bv2, const float* __restrict__ Ws1,
    const float* __restrict__ bs1, float* __restrict__ ws)
{
    int idx = blockIdx.x * 256 + threadIdx.x;
    if (idx < 131072) {
        // u[b][i][d] = 0.25 * (v[b,i,:] @ Ws1)[d]
        int d = idx & 63;
        const float* v = values + (idx >> 6) * 64;
        float s = 0.f;
#pragma unroll 8
        for (int k = 0; k < 64; k++) s = fmaf(v[k], Ws1[k * 64 + d], s);
        ws[OFF_U + idx] = 0.25f * s;
    } else if (idx < 135168) {
        // Wc = 0.5*Wv2@Ws1, bf16, swizzled into MFMA B-fragment order
        int e = idx - 131072;
        int j = e & 7, lane = (e >> 3) & 63, nt = (e >> 9) & 3, ks = e >> 11;
        int k = ks * 32 + ((lane >> 4) & 3) * 8 + j;
        int d = nt * 16 + (lane & 15);
        float s = 0.f;
#pragma unroll 8
        for (int m = 0; m < 64; m++) s = fmaf(Wv2[k * 64 + m], Ws1[m * 64 + d], s);
        ((unsigned short*)(ws + OFF_WCSW))[e] = bf16_rn(0.5f * s);
    } else if (idx < 136192) {
        // h-coefficients swizzled to A-fragment lane order
        int e = idx - 135168;
        int j = e & 7, lane = (e >> 3) & 63, ks = e >> 9;
        int k = ks * 32 + ((lane >> 4) & 3) * 8 + j;
        ws[OFF_CSA + e] = Wv1[k];
        ws[OFF_CSB + e] = Wv1[64 + k];
        ws[OFF_CSC + e] = bv1[k];
    } else if (idx < 136256) {
        int d = idx - 136192;
        float s = 0.f;
#pragma unroll 8
        for (int k = 0; k < 64; k++) s = fmaf(bv2[k], Ws1[k * 64 + d], s);
        ws[OFF_CC + d] = 0.5f * s + bs1[d];
    } else if (idx < 136264) {
        ((unsigned*)(ws + OFF_M))[idx - 136256] = 0u;   // identity for max-key
    } else if (idx < 136272) {
        ws[OFF_Z + idx - 136264] = 0.f;
    } else if (idx < 136784) {
        ws[OFF_SH + idx - 136272] = 0.f;
    } else if (idx < 137296) {
        ws[OFF_A2 + idx - 136784] = 0.f;
    }
}

// ---------------------------------------------------------------- pass1 ----
// grid: 8 batches * 128 i-tiles (2 rows each). block = 256 (4 waves).
__global__ __launch_bounds__(256, 2) void k_pass1(
    const float* __restrict__ pos, const float* __restrict__ Ws2,
    float* __restrict__ ws)
{
    __shared__ float2 ldsDB[2 * 256];
    __shared__ float  ldsCCU[2 * 64];
    __shared__ float  ldsWs2[64];
    __shared__ float  ldsPos[6];
    __shared__ float  ldsRed[256];

    int b  = blockIdx.x >> 7;
    int i0 = (blockIdx.x & 127) * 2;
    int t  = threadIdx.x;
    const float* uB = ws + OFF_U + b * (NN * DD);

    if (t < 6)  ldsPos[t] = pos[(b * 256 + i0) * 3 + t];
    if (t < 64) ldsWs2[t] = Ws2[t];
    if (t < 128) {
        int ii = t >> 6, d = t & 63;
        ldsCCU[t] = ws[OFF_CC + d] + uB[(i0 + ii) * 64 + d];
    }
    __syncthreads();

    {
        float px = pos[(b * 256 + t) * 3 + 0];
        float py = pos[(b * 256 + t) * 3 + 1];
        float pz = pos[(b * 256 + t) * 3 + 2];
#pragma unroll
        for (int ii = 0; ii < 2; ii++) {
            float ax = ldsPos[ii * 3 + 0], ay = ldsPos[ii * 3 + 1], az = ldsPos[ii * 3 + 2];
            float dot = ax * px + ay * py + az * pz;
            float cx = ay * pz - az * py;
            float cy = az * px - ax * pz;
            float cz = ax * py - ay * px;
            float biv = sqrtf(cx * cx + cy * cy + cz * cz + 1e-20f);
            ldsDB[ii * 256 + t] = make_float2(dot, biv);
        }
    }
    __syncthreads();

    int lane = t & 63, w = t >> 6;
    int q = lane >> 4, col = lane & 15;

    float cA[16], cB[16], cC[16];
    {
        const f32x4* pa0 = (const f32x4*)(ws + OFF_CSA + lane * 8);
        const f32x4* pa1 = (const f32x4*)(ws + OFF_CSA + 512 + lane * 8);
        ((f32x4*)cA)[0] = pa0[0]; ((f32x4*)cA)[1] = pa0[1];
        ((f32x4*)cA)[2] = pa1[0]; ((f32x4*)cA)[3] = pa1[1];
        const f32x4* pb0 = (const f32x4*)(ws + OFF_CSB + lane * 8);
        const f32x4* pb1 = (const f32x4*)(ws + OFF_CSB + 512 + lane * 8);
        ((f32x4*)cB)[0] = pb0[0]; ((f32x4*)cB)[1] = pb0[1];
        ((f32x4*)cB)[2] = pb1[0]; ((f32x4*)cB)[3] = pb1[1];
        const f32x4* pc0 = (const f32x4*)(ws + OFF_CSC + lane * 8);
        const f32x4* pc1 = (const f32x4*)(ws + OFF_CSC + 512 + lane * 8);
        ((f32x4*)cC)[0] = pc0[0]; ((f32x4*)cC)[1] = pc0[1];
        ((f32x4*)cC)[2] = pc1[0]; ((f32x4*)cC)[3] = pc1[1];
    }

    s16x8 bf[2][4];
    {
        const s16x8* wsw = (const s16x8*)(ws + OFF_WCSW);
#pragma unroll
        for (int ks = 0; ks < 2; ks++)
#pragma unroll
            for (int nt = 0; nt < 4; nt++)
                bf[ks][nt] = wsw[(ks * 4 + nt) * 64 + lane];
    }

    float wmax = -3.4e38f;
    float* scrow_base = ws + OFF_SC + (b * 256 + i0) * 256;

#pragma unroll
    for (int jt4 = 0; jt4 < 4; jt4++) {
        int jt = w * 4 + jt4;
        float uc[4][4];
#pragma unroll
        for (int r = 0; r < 4; r++) {
            int jl = jt * 16 + q * 4 + r;
#pragma unroll
            for (int nt = 0; nt < 4; nt++)
                uc[r][nt] = uB[jl * 64 + nt * 16 + col];
        }
#pragma unroll
        for (int ii = 0; ii < 2; ii++) {
            float2 db = ldsDB[ii * 256 + jt * 16 + col];
            s16x8 af[2];
#pragma unroll
            for (int ks = 0; ks < 2; ks++)
#pragma unroll
                for (int j = 0; j < 8; j++) {
                    float h = fmaf(db.x, cA[ks * 8 + j], fmaf(db.y, cB[ks * 8 + j], cC[ks * 8 + j]));
                    af[ks][j] = (short)bf16_rn(fmaxf(h, 0.f));
                }
            f32x4 acc[4];
#pragma unroll
            for (int nt = 0; nt < 4; nt++) acc[nt] = (f32x4){0.f, 0.f, 0.f, 0.f};
#pragma unroll
            for (int nt = 0; nt < 4; nt++) {
                acc[nt] = __builtin_amdgcn_mfma_f32_16x16x32_bf16(af[0], bf[0][nt], acc[nt], 0, 0, 0);
                acc[nt] = __builtin_amdgcn_mfma_f32_16x16x32_bf16(af[1], bf[1][nt], acc[nt], 0, 0, 0);
            }
            float tr[4] = {0.f, 0.f, 0.f, 0.f};
#pragma unroll
            for (int nt = 0; nt < 4; nt++) {
                float cu = ldsCCU[ii * 64 + nt * 16 + col];
                float w2 = ldsWs2[nt * 16 + col];
#pragma unroll
                for (int r = 0; r < 4; r++) {
                    float s = acc[nt][r] + cu + uc[r][nt];
                    tr[r] = fmaf(fmaxf(s, 0.f), w2, tr[r]);
                }
            }
#pragma unroll
            for (int m = 1; m < 16; m <<= 1) {
#pragma unroll
                for (int r = 0; r < 4; r++) tr[r] += __shfl_xor(tr[r], m);
            }
            wmax = fmaxf(wmax, fmaxf(fmaxf(tr[0], tr[1]), fmaxf(tr[2], tr[3])));
            if (col == 0) {
                float4 sc4 = make_float4(tr[0], tr[1], tr[2], tr[3]);
                *(float4*)(scrow_base + ii * 256 + jt * 16 + q * 4) = sc4;
            }
        }
    }

    // block max -> global atomic (order-encoded uint); wave shuffle first
#pragma unroll
    for (int md = 1; md < 64; md <<= 1) wmax = fmaxf(wmax, __shfl_xor(wmax, md));
    if (lane == 0) ldsRed[w] = wmax;
    __syncthreads();
    if (t == 0) {
        float bm = fmaxf(fmaxf(ldsRed[0], ldsRed[1]), fmaxf(ldsRed[2], ldsRed[3]));
        unsigned bits = __float_as_uint(bm);
        unsigned key = (bits & 0x80000000u) ? ~bits : (bits | 0x80000000u);
        atomicMax((unsigned*)(ws + OFF_M) + b, key);
    }
}

// ---------------------------------------------------------------- pass2 ----
// one block (256 thr) per (b,i): w_j=exp(s-m); atomically fold Sh, A2, Z.
__global__ __launch_bounds__(256) void k_pass2(
    const float* __restrict__ pos, const float* __restrict__ Wv1,
    const float* __restrict__ bv1, const float* __restrict__ values,
    float* __restrict__ ws)
{
    __shared__ float  ldsW[256];
    __shared__ float2 ldsDB[256];
    __shared__ float  ldsP[4][64];
    __shared__ float  ldsR[4];

    int b = blockIdx.x >> 8, i = blockIdx.x & 255;
    int t = threadIdx.x, w = t >> 6, lane = t & 63;

    unsigned key = ((const unsigned*)(ws + OFF_M))[b];
    unsigned mbits = (key & 0x80000000u) ? (key ^ 0x80000000u) : ~key;
    float m = __uint_as_float(mbits);

    const float* srow = ws + OFF_SC + (b * 256 + i) * 256;
    float wgt = __expf(srow[t] - m);
    ldsW[t] = wgt;
    {
        float ax = pos[(b * 256 + i) * 3 + 0];
        float ay = pos[(b * 256 + i) * 3 + 1];
        float az = pos[(b * 256 + i) * 3 + 2];
        float px = pos[(b * 256 + t) * 3 + 0];
        float py = pos[(b * 256 + t) * 3 + 1];
        float pz = pos[(b * 256 + t) * 3 + 2];
        float dot = ax * px + ay * py + az * pz;
        float cx = ay * pz - az * py;
        float cy = az * px - ax * pz;
        float cz = ax * py - ay * px;
        float biv = sqrtf(cx * cx + cy * cy + cz * cz + 1e-20f);
        ldsDB[t] = make_float2(dot, biv);
    }
    // wave-level rowsum, then 4-way LDS combine (no tree barriers)
    float r = wgt;
#pragma unroll
    for (int md = 1; md < 64; md <<= 1) r += __shfl_xor(r, md);
    if (lane == 0) ldsR[w] = r;
    __syncthreads();
    float rs = ldsR[0] + ldsR[1] + ldsR[2] + ldsR[3];

    float A = Wv1[lane], B = Wv1[64 + lane], C = bv1[lane];
    float acc = 0.f;
#pragma unroll 8
    for (int jj = 0; jj < 64; jj++) {
        int j = w * 64 + jj;
        float2 db = ldsDB[j];
        float h = fmaxf(fmaf(db.x, A, fmaf(db.y, B, C)), 0.f);
        acc = fmaf(ldsW[j], h, acc);
    }
    ldsP[w][lane] = acc;
    __syncthreads();
    if (t < 64) {
        float sh = ldsP[0][t] + ldsP[1][t] + ldsP[2][t] + ldsP[3][t];
        atomicAdd(ws + OFF_SH + b * 64 + t, sh);
        atomicAdd(ws + OFF_A2 + b * 64 + t, rs * values[(b * 256 + i) * 64 + t]);
    }
    if (t == 0) atomicAdd(ws + OFF_Z + b, rs);
}

// ------------------------------------------------------------------ out ----
__global__ __launch_bounds__(64) void k_out(
    const float* __restrict__ Wv2, const float* __restrict__ bv2,
    const float* __restrict__ ws, float* __restrict__ out)
{
    __shared__ float sh[64];
    int b = blockIdx.x, d = threadIdx.x;
    sh[d] = ws[OFF_SH + b * 64 + d];
    __syncthreads();
    float t1 = 0.f;
#pragma unroll 8
    for (int k = 0; k < 64; k++) t1 = fmaf(sh[k], Wv2[k * 64 + d], t1);
    float Z = ws[OFF_Z + b];
    out[b * 64 + d] = 0.5f * (t1 + ws[OFF_A2 + b * 64 + d]) / Z + 0.5f * bv2[d];
}

// ---------------------------------------------------------------- launch ---
extern "C" void kernel_launch(void* const* d_in, const int* in_sizes, int n_in,
                              void* d_out, int out_size, void* d_ws, size_t ws_size,
                              hipStream_t stream)
{
    const float* positions = (const float*)d_in[0];
    const float* values    = (const float*)d_in[1];
    const float* Wv1       = (const float*)d_in[2];
    const float* bv1       = (const float*)d_in[3];
    const float* Wv2       = (const float*)d_in[4];
    const float* bv2       = (const float*)d_in[5];
    const float* Ws1       = (const float*)d_in[6];
    const float* bs1       = (const float*)d_in[7];
    const float* Ws2       = (const float*)d_in[8];
    // d_in[9] = bs2: uniform shift on scores, cancels in softmax
    float* ws  = (float*)d_ws;
    float* out = (float*)d_out;

    k_setup<<<537, 256, 0, stream>>>(values, Wv1, bv1, Wv2, bv2, Ws1, bs1, ws);
    k_pass1<<<1024, 256, 0, stream>>>(positions, Ws2, ws);
    k_pass2<<<2048, 256, 0, stream>>>(positions, Wv1, bv1, values, ws);
    k_out<<<NB, 64, 0, stream>>>(Wv2, bv2, ws, out);
}

// Round 5
// 109.228 us; speedup vs baseline: 1.2152x; 1.2152x over previous
//
#include <hip/hip_runtime.h>
#include <hip/hip_bf16.h>

#define NB 8
#define NN 256
#define DD 64

// workspace layout (float offsets)
#define OFF_WCSW  0        // 2048 floats = 4096 bf16: B-fragments of Wc, swizzled
#define OFF_CSA   2048     // 1024 : Wv1 row0 swizzled to A-frag lane order
#define OFF_CSB   3072     // 1024 : Wv1 row1 swizzled
#define OFF_CSC   4096     // 1024 : bv1 swizzled
#define OFF_CC    5120     // 64   : cc[d] = 0.5*(bv2@Ws1)[d] + bs1[d]
#define OFF_MI    5184     // 2048 : per-row local max m_i
#define OFF_RSI   7232     // 2048 : per-row rowsum (local frame)
#define OFF_U     9280     // 131072 : u[b][i][d] = 0.25*(v@Ws1)
#define OFF_SHR   140352   // 131072 : Sh_i[k] per row (local frame)

typedef __attribute__((ext_vector_type(4))) float f32x4;
typedef __attribute__((ext_vector_type(8))) short s16x8;

static __device__ __forceinline__ unsigned short bf16_rn(float x) {
    unsigned u = __float_as_uint(x);
    u += 0x8000u;
    return (unsigned short)(u >> 16);
}

// ---------------------------------------------------------------- setup ----
__global__ __launch_bounds__(256) void k_setup(
    const float* __restrict__ values, const float* __restrict__ Wv1,
    const float* __restrict__ bv1, const float* __restrict__ Wv2,
    const float* __restrict__ bv2, const float* __restrict__ Ws1,
    const float* __restrict__ bs1, float* __restrict__ ws)
{
    int idx = blockIdx.x * 256 + threadIdx.x;
    if (idx < 131072) {
        // u[b][i][d] = 0.25 * (v[b,i,:] @ Ws1)[d]
        int d = idx & 63;
        const float* v = values + (idx >> 6) * 64;
        float s = 0.f;
#pragma unroll 8
        for (int k = 0; k < 64; k++) s = fmaf(v[k], Ws1[k * 64 + d], s);
        ws[OFF_U + idx] = 0.25f * s;
    } else if (idx < 135168) {
        // Wc = 0.5*Wv2@Ws1, bf16, swizzled into MFMA B-fragment order
        int e = idx - 131072;
        int j = e & 7, ln = (e >> 3) & 63, nt = (e >> 9) & 3, ks = e >> 11;
        int k = ks * 32 + ((ln >> 4) & 3) * 8 + j;
        int d = nt * 16 + (ln & 15);
        float s = 0.f;
#pragma unroll 8
        for (int m = 0; m < 64; m++) s = fmaf(Wv2[k * 64 + m], Ws1[m * 64 + d], s);
        ((unsigned short*)(ws + OFF_WCSW))[e] = bf16_rn(0.5f * s);
    } else if (idx < 136192) {
        // h-coefficients swizzled to A-fragment lane order
        int e = idx - 135168;
        int j = e & 7, ln = (e >> 3) & 63, ks = e >> 9;
        int k = ks * 32 + ((ln >> 4) & 3) * 8 + j;
        ws[OFF_CSA + e] = Wv1[k];
        ws[OFF_CSB + e] = Wv1[64 + k];
        ws[OFF_CSC + e] = bv1[k];
    } else if (idx < 136256) {
        int d = idx - 136192;
        float s = 0.f;
#pragma unroll 8
        for (int k = 0; k < 64; k++) s = fmaf(bv2[k], Ws1[k * 64 + d], s);
        ws[OFF_CC + d] = 0.5f * s + bs1[d];
    }
}

// ----------------------------------------------------------------- main ----
// 1024 blocks = 8 batches * 128 i-pairs; 256 threads (4 waves).
// Phase 1: MFMA score GEMM for 2 full rows -> LDS.
// Phase 2: row-local softmax + Sh accumulation -> per-row record in ws.
__global__ __launch_bounds__(256, 2) void k_main(
    const float* __restrict__ pos, const float* __restrict__ Wv1,
    const float* __restrict__ bv1, const float* __restrict__ Ws2,
    float* __restrict__ ws)
{
    __shared__ float2 ldsDB[2 * 256];   // (dot,biv) per (ii, j)
    __shared__ float  ldsS[2][256];     // scores for the 2 rows
    __shared__ float  ldsCCU[2 * 64];
    __shared__ float  ldsWs2[64];
    __shared__ float  ldsPos[6];
    __shared__ float  ldsRed[4];
    __shared__ float  ldsP[4][64];

    int b  = blockIdx.x >> 7;
    int i0 = (blockIdx.x & 127) * 2;
    int t  = threadIdx.x;
    int lane = t & 63, wv = t >> 6;
    const float* uB = ws + OFF_U + b * (NN * DD);

    if (t < 6)  ldsPos[t] = pos[(b * 256 + i0) * 3 + t];
    if (t < 64) ldsWs2[t] = Ws2[t];
    if (t < 128) {
        int ii = t >> 6, d = t & 63;
        ldsCCU[t] = ws[OFF_CC + d] + uB[(i0 + ii) * 64 + d];
    }
    __syncthreads();

    {   // dot/biv for both rows vs all j
        float px = pos[(b * 256 + t) * 3 + 0];
        float py = pos[(b * 256 + t) * 3 + 1];
        float pz = pos[(b * 256 + t) * 3 + 2];
#pragma unroll
        for (int ii = 0; ii < 2; ii++) {
            float ax = ldsPos[ii * 3 + 0], ay = ldsPos[ii * 3 + 1], az = ldsPos[ii * 3 + 2];
            float dot = ax * px + ay * py + az * pz;
            float cx = ay * pz - az * py;
            float cy = az * px - ax * pz;
            float cz = ax * py - ay * px;
            float biv = sqrtf(cx * cx + cy * cy + cz * cz + 1e-20f);
            ldsDB[ii * 256 + t] = make_float2(dot, biv);
        }
    }
    __syncthreads();

    int q = lane >> 4, col = lane & 15;

    // ---- phase 1: MFMA scores into LDS ----
    float cA[16], cB[16], cC[16];
    {
        const f32x4* pa0 = (const f32x4*)(ws + OFF_CSA + lane * 8);
        const f32x4* pa1 = (const f32x4*)(ws + OFF_CSA + 512 + lane * 8);
        ((f32x4*)cA)[0] = pa0[0]; ((f32x4*)cA)[1] = pa0[1];
        ((f32x4*)cA)[2] = pa1[0]; ((f32x4*)cA)[3] = pa1[1];
        const f32x4* pb0 = (const f32x4*)(ws + OFF_CSB + lane * 8);
        const f32x4* pb1 = (const f32x4*)(ws + OFF_CSB + 512 + lane * 8);
        ((f32x4*)cB)[0] = pb0[0]; ((f32x4*)cB)[1] = pb0[1];
        ((f32x4*)cB)[2] = pb1[0]; ((f32x4*)cB)[3] = pb1[1];
        const f32x4* pc0 = (const f32x4*)(ws + OFF_CSC + lane * 8);
        const f32x4* pc1 = (const f32x4*)(ws + OFF_CSC + 512 + lane * 8);
        ((f32x4*)cC)[0] = pc0[0]; ((f32x4*)cC)[1] = pc0[1];
        ((f32x4*)cC)[2] = pc1[0]; ((f32x4*)cC)[3] = pc1[1];
    }
    s16x8 bfr[2][4];
    {
        const s16x8* wsw = (const s16x8*)(ws + OFF_WCSW);
#pragma unroll
        for (int ks = 0; ks < 2; ks++)
#pragma unroll
            for (int nt = 0; nt < 4; nt++)
                bfr[ks][nt] = wsw[(ks * 4 + nt) * 64 + lane];
    }

#pragma unroll
    for (int jt4 = 0; jt4 < 4; jt4++) {
        int jt = wv * 4 + jt4;
        float uc[4][4];
#pragma unroll
        for (int r = 0; r < 4; r++) {
            int jl = jt * 16 + q * 4 + r;
#pragma unroll
            for (int nt = 0; nt < 4; nt++)
                uc[r][nt] = uB[jl * 64 + nt * 16 + col];
        }
#pragma unroll
        for (int ii = 0; ii < 2; ii++) {
            float2 db = ldsDB[ii * 256 + jt * 16 + col];
            s16x8 af[2];
#pragma unroll
            for (int ks = 0; ks < 2; ks++)
#pragma unroll
                for (int j = 0; j < 8; j++) {
                    float h = fmaf(db.x, cA[ks * 8 + j], fmaf(db.y, cB[ks * 8 + j], cC[ks * 8 + j]));
                    af[ks][j] = (short)bf16_rn(fmaxf(h, 0.f));
                }
            f32x4 acc[4];
#pragma unroll
            for (int nt = 0; nt < 4; nt++) acc[nt] = (f32x4){0.f, 0.f, 0.f, 0.f};
#pragma unroll
            for (int nt = 0; nt < 4; nt++) {
                acc[nt] = __builtin_amdgcn_mfma_f32_16x16x32_bf16(af[0], bfr[0][nt], acc[nt], 0, 0, 0);
                acc[nt] = __builtin_amdgcn_mfma_f32_16x16x32_bf16(af[1], bfr[1][nt], acc[nt], 0, 0, 0);
            }
            float tr[4] = {0.f, 0.f, 0.f, 0.f};
#pragma unroll
            for (int nt = 0; nt < 4; nt++) {
                float cu = ldsCCU[ii * 64 + nt * 16 + col];
                float w2 = ldsWs2[nt * 16 + col];
#pragma unroll
                for (int r = 0; r < 4; r++) {
                    float s = acc[nt][r] + cu + uc[r][nt];
                    tr[r] = fmaf(fmaxf(s, 0.f), w2, tr[r]);
                }
            }
#pragma unroll
            for (int m = 1; m < 16; m <<= 1) {
#pragma unroll
                for (int r = 0; r < 4; r++) tr[r] += __shfl_xor(tr[r], m);
            }
            if (col == 0) {
                float4 sc4 = make_float4(tr[0], tr[1], tr[2], tr[3]);
                *(float4*)&ldsS[ii][jt * 16 + q * 4] = sc4;
            }
        }
    }
    __syncthreads();

    // ---- phase 2: row-local softmax + Sh ----
    float A = Wv1[lane], B = Wv1[64 + lane], C = bv1[lane];
#pragma unroll
    for (int ii = 0; ii < 2; ii++) {
        float sv = ldsS[ii][t];                 // score for j = t
        float wm = sv;
#pragma unroll
        for (int md = 1; md < 64; md <<= 1) wm = fmaxf(wm, __shfl_xor(wm, md));
        if (lane == 0) ldsRed[wv] = wm;
        __syncthreads();
        float m_row = fmaxf(fmaxf(ldsRed[0], ldsRed[1]), fmaxf(ldsRed[2], ldsRed[3]));
        float wgt = __expf(sv - m_row);         // lane jj of wave wv holds w for j=wv*64+jj
        float rsp = wgt;
#pragma unroll
        for (int md = 1; md < 64; md <<= 1) rsp += __shfl_xor(rsp, md);
        __syncthreads();                         // ldsRed reuse
        if (lane == 0) ldsRed[wv] = rsp;
        __syncthreads();
        float rowsum = ldsRed[0] + ldsRed[1] + ldsRed[2] + ldsRed[3];

        float acc = 0.f;                         // lane = k; wave sums its 64 j's
#pragma unroll 8
        for (int jj = 0; jj < 64; jj++) {
            float w = __shfl(wgt, jj);
            float2 db = ldsDB[ii * 256 + wv * 64 + jj];
            float h = fmaxf(fmaf(db.x, A, fmaf(db.y, B, C)), 0.f);
            acc = fmaf(w, h, acc);
        }
        ldsP[wv][lane] = acc;
        __syncthreads();
        int row = b * 256 + i0 + ii;
        if (t < 64)
            ws[OFF_SHR + row * 64 + t] = ldsP[0][t] + ldsP[1][t] + ldsP[2][t] + ldsP[3][t];
        if (t == 0) { ws[OFF_MI + row] = m_row; ws[OFF_RSI + row] = rowsum; }
        __syncthreads();                         // ldsRed/ldsP reuse next ii
    }
}

// ---------------------------------------------------------------- final ----
// one block per batch: fold 256 row-records into the output.
__global__ __launch_bounds__(256) void k_final(
    const float* __restrict__ values, const float* __restrict__ Wv2,
    const float* __restrict__ bv2, const float* __restrict__ ws,
    float* __restrict__ out)
{
    __shared__ float scl[256], zl[256], red[4], pS[4][64], pA[4][64], shv[64], a2v[64];
    int b = blockIdx.x, t = threadIdx.x, wv = t >> 6, lane = t & 63;

    float mi = ws[OFF_MI + b * 256 + t];
    float wm = mi;
#pragma unroll
    for (int md = 1; md < 64; md <<= 1) wm = fmaxf(wm, __shfl_xor(wm, md));
    if (lane == 0) red[wv] = wm;
    __syncthreads();
    float M = fmaxf(fmaxf(red[0], red[1]), fmaxf(red[2], red[3]));

    float rs = ws[OFF_RSI + b * 256 + t];
    float sc = __expf(mi - M);
    float zt = sc * rs;
    scl[t] = sc; zl[t] = zt;
    float zp = zt;
#pragma unroll
    for (int md = 1; md < 64; md <<= 1) zp += __shfl_xor(zp, md);
    __syncthreads();                  // red reuse
    if (lane == 0) red[wv] = zp;
    __syncthreads();
    float Z = red[0] + red[1] + red[2] + red[3];

    float accS = 0.f, accA = 0.f;
    const float* shrB = ws + OFF_SHR + b * 256 * 64;
    const float* vB   = values + b * 256 * 64;
#pragma unroll 4
    for (int jj = 0; jj < 64; jj++) {
        int row = wv * 64 + jj;
        accS = fmaf(scl[row], shrB[row * 64 + lane], accS);
        accA = fmaf(zl[row],  vB[row * 64 + lane],  accA);
    }
    pS[wv][lane] = accS; pA[wv][lane] = accA;
    __syncthreads();
    if (t < 64) {
        shv[t] = pS[0][t] + pS[1][t] + pS[2][t] + pS[3][t];
        a2v[t] = pA[0][t] + pA[1][t] + pA[2][t] + pA[3][t];
    }
    __syncthreads();
    if (t < 64) {
        float t1 = 0.f;
#pragma unroll 8
        for (int k = 0; k < 64; k++) t1 = fmaf(shv[k], Wv2[k * 64 + t], t1);
        out[b * 64 + t] = 0.5f * (t1 + a2v[t]) / Z + 0.5f * bv2[t];
    }
}

// ---------------------------------------------------------------- launch ---
extern "C" void kernel_launch(void* const* d_in, const int* in_sizes, int n_in,
                              void* d_out, int out_size, void* d_ws, size_t ws_size,
                              hipStream_t stream)
{
    const float* positions = (const float*)d_in[0];
    const float* values    = (const float*)d_in[1];
    const float* Wv1       = (const float*)d_in[2];
    const float* bv1       = (const float*)d_in[3];
    const float* Wv2       = (const float*)d_in[4];
    const float* bv2       = (const float*)d_in[5];
    const float* Ws1       = (const float*)d_in[6];
    const float* bs1       = (const float*)d_in[7];
    const float* Ws2       = (const float*)d_in[8];
    // d_in[9] = bs2: uniform shift on scores, cancels in softmax
    float* ws  = (float*)d_ws;
    float* out = (float*)d_out;

    k_setup<<<533, 256, 0, stream>>>(values, Wv1, bv1, Wv2, bv2, Ws1, bs1, ws);
    k_main<<<1024, 256, 0, stream>>>(positions, Wv1, bv1, Ws2, ws);
    k_final<<<NB, 256, 0, stream>>>(values, Wv2, bv2, ws, out);
}

// Round 7
// 105.560 us; speedup vs baseline: 1.2575x; 1.0347x over previous
//
#include <hip/hip_runtime.h>
#include <hip/hip_bf16.h>
#include <hip/hip_fp16.h>

#define NB 8
#define NN 256
#define DD 64

// workspace layout (float offsets)
#define OFF_WCF   0        // 2048 f = 4096 f16 : Wc B-frags [ks][nt][lane][8]
#define OFF_W1F   2048     // 2048 f = 4096 f16 : 0.25*Ws1 B-frags, same order
#define OFF_CSF   4096     // 1536 f = 3072 f16 : h-coefs per lane [lane][coef][kslot16], stride 48
#define OFF_CC    5632     // 64   : cc[d] = 0.5*(bv2@Ws1)[d] + bs1[d]
#define OFF_MI    5696     // 2048 : per-row local max
#define OFF_RSI   7744     // 2048 : per-row rowsum (local frame)
#define OFF_SHR   9792     // 131072 : per-row Sh[64] (local frame)
#define OFF_VF    140864   // 65536 f = 131072 f16 : values cast to f16

typedef __attribute__((ext_vector_type(4))) float f32x4;
typedef _Float16 f16x8 __attribute__((ext_vector_type(8)));

// ---------------------------------------------------------------- setup ----
__global__ __launch_bounds__(256) void k_setup(
    const float* __restrict__ values, const float* __restrict__ Wv1,
    const float* __restrict__ bv1, const float* __restrict__ Wv2,
    const float* __restrict__ bv2, const float* __restrict__ Ws1,
    const float* __restrict__ bs1, float* __restrict__ ws)
{
    int idx = blockIdx.x * 256 + threadIdx.x;
    if (idx < 131072) {
        ((_Float16*)(ws + OFF_VF))[idx] = (_Float16)values[idx];
    } else if (idx < 135168) {
        // Wc = 0.5*Wv2@Ws1 -> f16 B-fragment order
        int e = idx - 131072;
        int j = e & 7, ln = (e >> 3) & 63, nt = (e >> 9) & 3, ks = e >> 11;
        int k = ks * 32 + (ln >> 4) * 8 + j;
        int d = nt * 16 + (ln & 15);
        float s = 0.f;
#pragma unroll 8
        for (int m = 0; m < 64; m++) s = fmaf(Wv2[k * 64 + m], Ws1[m * 64 + d], s);
        ((_Float16*)(ws + OFF_WCF))[e] = (_Float16)(0.5f * s);
    } else if (idx < 139264) {
        // 0.25*Ws1 -> f16 B-fragment order
        int e = idx - 135168;
        int j = e & 7, ln = (e >> 3) & 63, nt = (e >> 9) & 3, ks = e >> 11;
        int k = ks * 32 + (ln >> 4) * 8 + j;
        int d = nt * 16 + (ln & 15);
        ((_Float16*)(ws + OFF_W1F))[e] = (_Float16)(0.25f * Ws1[k * 64 + d]);
    } else if (idx < 142336) {
        // h-coefs: stride-48 per lane: [lane][coef(3)][kslot(16)]
        int e = idx - 139264;          // 0..3071
        int ln = e / 48;
        int rem = e - ln * 48;
        int coef = rem >> 4, kslot = rem & 15;
        int ks = kslot >> 3, j = kslot & 7;
        int k = ks * 32 + (ln >> 4) * 8 + j;
        float v = (coef == 0) ? Wv1[k] : (coef == 1) ? Wv1[64 + k] : bv1[k];
        ((_Float16*)(ws + OFF_CSF))[ln * 48 + coef * 16 + kslot] = (_Float16)v;
    } else if (idx < 142400) {
        int d = idx - 142336;
        float s = 0.f;
#pragma unroll 8
        for (int k = 0; k < 64; k++) s = fmaf(bv2[k], Ws1[k * 64 + d], s);
        ws[OFF_CC + d] = 0.5f * s + bs1[d];
    }
}

// ----------------------------------------------------------------- main ----
// 1024 blocks = 8 batches * 128 i-pairs; 256 threads (4 waves).
__global__ __launch_bounds__(256, 4) void k_main(
    const float* __restrict__ pos, const float* __restrict__ Wv1,
    const float* __restrict__ bv1, const float* __restrict__ Ws2,
    float* __restrict__ ws)
{
    __shared__ float2   ldsDB[2 * 256];   // (dot,biv)
    __shared__ float    ldsS[2][256];     // scores, then weights
    __shared__ float    ldsCCU[2 * 64];   // cc + u_i
    __shared__ float    ldsWs2[64];
    __shared__ float    ldsPos[6];
    __shared__ float    ldsRed[4];
    __shared__ float    ldsP[4][64];
    __shared__ _Float16 ldsW1[4096];      // 0.25*Ws1 B-frags

    int b  = blockIdx.x >> 7;
    int i0 = (blockIdx.x & 127) * 2;
    int t  = threadIdx.x;
    int lane = t & 63, wv = t >> 6;
    int q = lane >> 4, col = lane & 15;

    const _Float16* vf = (const _Float16*)(ws + OFF_VF);

    // ---- stage constants ----
    {   // ldsW1: 2048 floats as float4
        const float4* src = (const float4*)(ws + OFF_W1F);
        float4* dst = (float4*)ldsW1;
        dst[t] = src[t];
        dst[256 + t] = src[256 + t];
    }
    if (t < 6)  ldsPos[t] = pos[(b * 256 + i0) * 3 + t];
    if (t < 64) ldsWs2[t] = Ws2[t];
    if (t < 128) ldsCCU[t] = ws[OFF_CC + (t & 63)];

    // per-lane h-coefs (f16 packed): 16 kslots x {A,B,C}
    f16x8 cfA[2], cfB[2], cfC[2];
    {
        const f16x8* cs = (const f16x8*)((const _Float16*)(ws + OFF_CSF) + lane * 48);
        cfA[0] = cs[0]; cfA[1] = cs[1];
        cfB[0] = cs[2]; cfB[1] = cs[3];
        cfC[0] = cs[4]; cfC[1] = cs[5];
    }
    // Wc B-frags in registers
    f16x8 wcf[2][4];
    {
        const f16x8* p = (const f16x8*)(ws + OFF_WCF);
#pragma unroll
        for (int ks = 0; ks < 2; ks++)
#pragma unroll
            for (int nt = 0; nt < 4; nt++)
                wcf[ks][nt] = p[(ks * 4 + nt) * 64 + lane];
    }
    __syncthreads();

    {   // dot/biv for both rows vs all j
        float px = pos[(b * 256 + t) * 3 + 0];
        float py = pos[(b * 256 + t) * 3 + 1];
        float pz = pos[(b * 256 + t) * 3 + 2];
#pragma unroll
        for (int ii = 0; ii < 2; ii++) {
            float ax = ldsPos[ii * 3 + 0], ay = ldsPos[ii * 3 + 1], az = ldsPos[ii * 3 + 2];
            float dot = ax * px + ay * py + az * pz;
            float cx = ay * pz - az * py;
            float cy = az * px - ax * pz;
            float cz = ax * py - ay * px;
            float biv = sqrtf(cx * cx + cy * cy + cz * cz + 1e-20f);
            ldsDB[ii * 256 + t] = make_float2(dot, biv);
        }
    }

    // ---- u_i via MFMA (wave 0 only): A rows 0..1 = v_{i0}, v_{i0+1} ----
    if (wv == 0) {
        const f16x8* w1 = (const f16x8*)ldsW1;
        f16x8 afu[2];
#pragma unroll
        for (int ks = 0; ks < 2; ks++) {
            if (col < 2)
                afu[ks] = ((const f16x8*)(vf + (b * 256 + i0 + col) * 64))[ks * 4 + q];
            else
                afu[ks] = (f16x8)(_Float16)0.f;
        }
        f32x4 ua[4];
#pragma unroll
        for (int nt = 0; nt < 4; nt++) {
            ua[nt] = (f32x4){0.f, 0.f, 0.f, 0.f};
            ua[nt] = __builtin_amdgcn_mfma_f32_16x16x32_f16(afu[0], w1[(0 * 4 + nt) * 64 + lane], ua[nt], 0, 0, 0);
            ua[nt] = __builtin_amdgcn_mfma_f32_16x16x32_f16(afu[1], w1[(1 * 4 + nt) * 64 + lane], ua[nt], 0, 0, 0);
        }
        if (q == 0) {   // D rows 0..1 live in quad 0, regs r=0,1; single wave -> no race
#pragma unroll
            for (int nt = 0; nt < 4; nt++) {
#pragma unroll
                for (int r = 0; r < 2; r++)
                    ldsCCU[r * 64 + nt * 16 + col] += ua[nt][r];
            }
        }
    }
    __syncthreads();

    // ---- phase 1: K=128 MFMA GEMM S = [h|v] @ [Wc; 0.25 Ws1] ----
    const f16x8* w1 = (const f16x8*)ldsW1;

#pragma unroll
    for (int jt4 = 0; jt4 < 4; jt4++) {
        int jt = wv * 4 + jt4;
        // v A-frags for this j-tile (shared across ii)
        f16x8 av[2];
#pragma unroll
        for (int ks = 0; ks < 2; ks++)
            av[ks] = ((const f16x8*)(vf + (b * 256 + jt * 16 + col) * 64))[ks * 4 + q];

#pragma unroll
        for (int ii = 0; ii < 2; ii++) {
            float2 db = ldsDB[ii * 256 + jt * 16 + col];
            _Float16 dh = (_Float16)db.x, bh = (_Float16)db.y;
            f16x8 d8, b8;
#pragma unroll
            for (int p = 0; p < 8; p++) { d8[p] = dh; b8[p] = bh; }
            f16x8 af[2];
#pragma unroll
            for (int ks = 0; ks < 2; ks++) {
                f16x8 h = d8 * cfA[ks] + b8 * cfB[ks] + cfC[ks];
                af[ks] = __builtin_elementwise_max(h, (f16x8)(_Float16)0.f);
            }
            f32x4 acc[4];
#pragma unroll
            for (int nt = 0; nt < 4; nt++) {
                acc[nt] = (f32x4){0.f, 0.f, 0.f, 0.f};
                acc[nt] = __builtin_amdgcn_mfma_f32_16x16x32_f16(av[0], w1[(0 * 4 + nt) * 64 + lane], acc[nt], 0, 0, 0);
                acc[nt] = __builtin_amdgcn_mfma_f32_16x16x32_f16(av[1], w1[(1 * 4 + nt) * 64 + lane], acc[nt], 0, 0, 0);
                acc[nt] = __builtin_amdgcn_mfma_f32_16x16x32_f16(af[0], wcf[0][nt], acc[nt], 0, 0, 0);
                acc[nt] = __builtin_amdgcn_mfma_f32_16x16x32_f16(af[1], wcf[1][nt], acc[nt], 0, 0, 0);
            }
            // epilogue: + (cc + u_i), relu, *Ws2, reduce over d
            float tr[4] = {0.f, 0.f, 0.f, 0.f};
#pragma unroll
            for (int nt = 0; nt < 4; nt++) {
                float cu = ldsCCU[ii * 64 + nt * 16 + col];
                float w2 = ldsWs2[nt * 16 + col];
#pragma unroll
                for (int r = 0; r < 4; r++) {
                    float s = acc[nt][r] + cu;
                    tr[r] = fmaf(fmaxf(s, 0.f), w2, tr[r]);
                }
            }
#pragma unroll
            for (int m = 1; m < 16; m <<= 1) {
#pragma unroll
                for (int r = 0; r < 4; r++) tr[r] += __shfl_xor(tr[r], m);
            }
            if (col == 0) {
                float4 sc4 = make_float4(tr[0], tr[1], tr[2], tr[3]);
                *(float4*)&ldsS[ii][jt * 16 + q * 4] = sc4;
            }
        }
    }
    __syncthreads();

    // ---- phase 2: row-local softmax + Sh ----
    float A = Wv1[lane], B = Wv1[64 + lane], C = bv1[lane];
#pragma unroll
    for (int ii = 0; ii < 2; ii++) {
        float sv = ldsS[ii][t];
        float wm = sv;
#pragma unroll
        for (int md = 1; md < 64; md <<= 1) wm = fmaxf(wm, __shfl_xor(wm, md));
        if (lane == 0) ldsRed[wv] = wm;
        __syncthreads();
        float m_row = fmaxf(fmaxf(ldsRed[0], ldsRed[1]), fmaxf(ldsRed[2], ldsRed[3]));
        float wgt = __expf(sv - m_row);
        float rsp = wgt;
#pragma unroll
        for (int md = 1; md < 64; md <<= 1) rsp += __shfl_xor(rsp, md);
        ldsS[ii][t] = wgt;                 // own-slot overwrite, safe
        __syncthreads();                   // ldsRed reuse + wgt visible
        if (lane == 0) ldsRed[wv] = rsp;
        __syncthreads();
        float rowsum = ldsRed[0] + ldsRed[1] + ldsRed[2] + ldsRed[3];

        float acc = 0.f;                   // lane = k; wave sums its 64 j's
#pragma unroll 8
        for (int jj = 0; jj < 64; jj++) {
            int j = wv * 64 + jj;
            float w = ldsS[ii][j];         // broadcast read
            float2 db = ldsDB[ii * 256 + j];
            float h = fmaxf(fmaf(db.x, A, fmaf(db.y, B, C)), 0.f);
            acc = fmaf(w, h, acc);
        }
        ldsP[wv][lane] = acc;
        __syncthreads();
        int row = b * 256 + i0 + ii;
        if (t < 64)
            ws[OFF_SHR + row * 64 + t] = ldsP[0][t] + ldsP[1][t] + ldsP[2][t] + ldsP[3][t];
        if (t == 0) { ws[OFF_MI + row] = m_row; ws[OFF_RSI + row] = rowsum; }
        __syncthreads();
    }
}

// ---------------------------------------------------------------- final ----
__global__ __launch_bounds__(256) void k_final(
    const float* __restrict__ values, const float* __restrict__ Wv2,
    const float* __restrict__ bv2, const float* __restrict__ ws,
    float* __restrict__ out)
{
    __shared__ float scl[256], zl[256], red[4], pS[4][64], pA[4][64], shv[64], a2v[64];
    int b = blockIdx.x, t = threadIdx.x, wv = t >> 6, lane = t & 63;

    float mi = ws[OFF_MI + b * 256 + t];
    float wm = mi;
#pragma unroll
    for (int md = 1; md < 64; md <<= 1) wm = fmaxf(wm, __shfl_xor(wm, md));
    if (lane == 0) red[wv] = wm;
    __syncthreads();
    float M = fmaxf(fmaxf(red[0], red[1]), fmaxf(red[2], red[3]));

    float rs = ws[OFF_RSI + b * 256 + t];
    float sc = __expf(mi - M);
    float zt = sc * rs;
    scl[t] = sc; zl[t] = zt;
    float zp = zt;
#pragma unroll
    for (int md = 1; md < 64; md <<= 1) zp += __shfl_xor(zp, md);
    __syncthreads();
    if (lane == 0) red[wv] = zp;
    __syncthreads();
    float Z = red[0] + red[1] + red[2] + red[3];

    float accS = 0.f, accA = 0.f;
    const float* shrB = ws + OFF_SHR + b * 256 * 64;
    const float* vB   = values + b * 256 * 64;
#pragma unroll 4
    for (int jj = 0; jj < 64; jj++) {
        int row = wv * 64 + jj;
        accS = fmaf(scl[row], shrB[row * 64 + lane], accS);
        accA = fmaf(zl[row],  vB[row * 64 + lane],  accA);
    }
    pS[wv][lane] = accS; pA[wv][lane] = accA;
    __syncthreads();
    if (t < 64) {
        shv[t] = pS[0][t] + pS[1][t] + pS[2][t] + pS[3][t];
        a2v[t] = pA[0][t] + pA[1][t] + pA[2][t] + pA[3][t];
    }
    __syncthreads();
    if (t < 64) {
        float t1 = 0.f;
#pragma unroll 8
        for (int k = 0; k < 64; k++) t1 = fmaf(shv[k], Wv2[k * 64 + t], t1);
        out[b * 64 + t] = 0.5f * (t1 + a2v[t]) / Z + 0.5f * bv2[t];
    }
}

// ---------------------------------------------------------------- launch ---
extern "C" void kernel_launch(void* const* d_in, const int* in_sizes, int n_in,
                              void* d_out, int out_size, void* d_ws, size_t ws_size,
                              hipStream_t stream)
{
    const float* positions = (const float*)d_in[0];
    const float* values    = (const float*)d_in[1];
    const float* Wv1       = (const float*)d_in[2];
    const float* bv1       = (const float*)d_in[3];
    const float* Wv2       = (const float*)d_in[4];
    const float* bv2       = (const float*)d_in[5];
    const float* Ws1       = (const float*)d_in[6];
    const float* bs1       = (const float*)d_in[7];
    const float* Ws2       = (const float*)d_in[8];
    // d_in[9] = bs2: uniform shift on scores, cancels in softmax
    float* ws  = (float*)d_ws;
    float* out = (float*)d_out;

    k_setup<<<557, 256, 0, stream>>>(values, Wv1, bv1, Wv2, bv2, Ws1, bs1, ws);
    k_main<<<1024, 256, 0, stream>>>(positions, Wv1, bv1, Ws2, ws);
    k_final<<<NB, 256, 0, stream>>>(values, Wv2, bv2, ws, out);
}